// Round 5
// baseline (126.770 us; speedup 1.0000x reference)
//
#include <hip/hip_runtime.h>
#include <cstdint>

#define NQ 16
#define NL 4
#define NOUT 784
#define NCHUNK 16
#define MAXBIN 256

// ---------------------------------------------------------------------------
// Circuit algebra (verified by round-1 pass, absmax 9.8e-4):
//   <Z_q>_s = 2^-16 Σ_x cos( zpart_s(x) + d_q(x) )
//   d_q(x)     = Σ_{k: pc(v_k & m_q) odd} W_k (-1)^{pc(v_k & x)}
//   zpart_s(x) = Σ_{j in m_q} (-1)^{x_j} z_sj      (depends ONLY on x|m_q bits)
// Regroup by bin = pext(x, m_q)  (popcount(m_q) <= 7 for this circuit):
//   <Z_q>_s = 2^-16 Re Σ_bin e^{i zpart_s(bin)} * P_q[bin]
//   P_q[bin] = Σ_{x: pext(x,m_q)=bin} e^{i d_q(x)}     (sample-independent!)
// ---------------------------------------------------------------------------
struct Tables {
  uint16_t m[NQ];
  int32_t  cnt[NQ];
  int32_t  pc[NQ];
  uint8_t  pos[NQ][16];
  uint16_t kmask[NQ][NL*NQ];
  uint8_t  kidx[NQ][NL*NQ];
};

constexpr Tables make_tables() {
  Tables T{};
  uint16_t v[NL*NQ] = {};
  for (int l = 0; l < NL; l++)
    for (int q = 0; q < NQ; q++) {
      unsigned vv = 1u << q;
      for (int L = l - 1; L >= 0; --L)
        for (int k = NQ - 1; k >= 0; --k) {
          unsigned t = (unsigned)((k + 1) & (NQ - 1));
          if ((vv >> k) & 1u) vv ^= (1u << t);
        }
      v[l*NQ + q] = (uint16_t)vv;
    }
  for (int q = 0; q < NQ; q++) {
    unsigned mm = 1u << q;
    for (int L = NL - 1; L >= 0; --L)
      for (int k = NQ - 1; k >= 0; --k) {
        unsigned t = (unsigned)((k + 1) & (NQ - 1));
        if ((mm >> t) & 1u) mm ^= (1u << k);
      }
    T.m[q] = (uint16_t)mm;
  }
  for (int q = 0; q < NQ; q++) {
    int c = 0;
    for (int i = 0; i < NL*NQ; i++) {
      unsigned inter = (unsigned)(v[i] & T.m[q]);
      int pcnt = 0;
      for (int b = 0; b < 16; b++) pcnt += (int)((inter >> b) & 1u);
      if (pcnt & 1) { T.kmask[q][c] = v[i]; T.kidx[q][c] = (uint8_t)i; c++; }
    }
    T.cnt[q] = c;
  }
  for (int q = 0; q < NQ; q++) {
    int c = 0;
    for (int b = 0; b < 16; b++)
      if ((T.m[q] >> b) & 1u) { T.pos[q][c] = (uint8_t)b; c++; }
    T.pc[q] = c;
  }
  return T;
}

constexpr Tables H_TAB = make_tables();
constexpr int max_pc() {
  int mx = 0;
  for (int q = 0; q < NQ; q++) if (H_TAB.pc[q] > mx) mx = H_TAB.pc[q];
  return mx;
}
static_assert(max_pc() <= 8, "bin table overflow — hand analysis wrong");
__constant__ Tables TAB = H_TAB;

// kP: fold kernel. Block b = (q, chunk of 4096 x-values). For each x:
// d = Σ ±W, (c,s) = sincos(d), LDS-atomic into bins[pext(x,m)].
// Writes per-block partial bins to Pp[b][bin][2] — every slot a thread
// reads later is unconditionally written here (no init/poison hazard).
__global__ __launch_bounds__(256) void kP(const float* __restrict__ W,
                                          float* __restrict__ Pp) {
  __shared__ float sW[NL*NQ];
  __shared__ float binC[MAXBIN], binS[MAXBIN];
  int t = threadIdx.x;
  int b = blockIdx.x;              // 256 = 16 q * 16 chunks
  int q = b >> 4, chunk = b & 15;
  if (t < NL*NQ) sW[t] = W[t];
  binC[t] = 0.f; binS[t] = 0.f;    // t covers all 256 bin slots
  __syncthreads();
  int n  = TAB.cnt[q];
  int pc = TAB.pc[q];
  for (int i = 0; i < 16; i++) {
    unsigned x = ((unsigned)chunk << 12) | ((unsigned)i << 8) | (unsigned)t;
    float d = 0.f;
    for (int k = 0; k < n; k++) {
      unsigned msk = TAB.kmask[q][k];
      float w = sW[TAB.kidx[q][k]];
      unsigned sgn = (unsigned)(__popc(msk & x) & 1) << 31;
      d += __uint_as_float(__float_as_uint(w) ^ sgn);
    }
    float sn, cs;
    __sincosf(d, &sn, &cs);
    unsigned bin = 0;
    for (int j = 0; j < pc; j++) bin |= ((x >> TAB.pos[q][j]) & 1u) << j;
    atomicAdd(&binC[bin], cs);
    atomicAdd(&binS[bin], sn);
  }
  __syncthreads();
  int nb = 1 << pc;
  if (t < nb) {
    Pp[(((unsigned)b << 8) + (unsigned)t) * 2 + 0] = binC[t];
    Pp[(((unsigned)b << 8) + (unsigned)t) * 2 + 1] = binS[t];
  }
}

// kBC: one block per sample. Phase A: for each q, contract bins with
// e^{i zpart}; Phase B: 784-wide linear + tanh.
__global__ __launch_bounds__(256) void kBC(const float* __restrict__ z,
                                           const float* __restrict__ Pp,
                                           const float* __restrict__ wl,
                                           const float* __restrict__ bl,
                                           float* __restrict__ out) {
  __shared__ float sz[NQ];
  __shared__ float szq[NQ];
  __shared__ float red[4];
  int s = blockIdx.x;              // 64 samples
  int t = threadIdx.x;
  if (t < NQ) sz[t] = z[s*NQ + t];
  __syncthreads();
  for (int q = 0; q < NQ; q++) {
    int pc  = TAB.pc[q];
    int nb  = 1 << pc;
    int bin = t & (nb - 1);
    int cg  = t >> pc;             // chunk group
    int ncg = 256 >> pc;           // number of chunk groups
    float pC = 0.f, pS = 0.f;
    for (int c = cg; c < NCHUNK; c += ncg) {
      unsigned idx = ((((unsigned)(q*NCHUNK + c)) << 8) + (unsigned)bin) * 2;
      pC += Pp[idx];
      pS += Pp[idx + 1];
    }
    float zp = 0.f;
    for (int j = 0; j < pc; j++) {
      float v = sz[TAB.pos[q][j]];
      zp += ((bin >> j) & 1) ? -v : v;
    }
    float szn, cz;
    __sincosf(zp, &szn, &cz);
    float term = pC * cz - pS * szn;
    for (int off = 32; off > 0; off >>= 1) term += __shfl_down(term, off, 64);
    if ((t & 63) == 0) red[t >> 6] = term;
    __syncthreads();
    if (t == 0) szq[q] = (red[0] + red[1] + red[2] + red[3]) * (1.0f / 65536.0f);
    __syncthreads();
  }
  for (int o = t; o < NOUT; o += 256) {
    float acc = bl[o];
    const float* wr = wl + o*NQ;
    #pragma unroll
    for (int j = 0; j < NQ; j++) acc += szq[j] * wr[j];
    out[s*NOUT + o] = tanhf(acc);
  }
}

extern "C" void kernel_launch(void* const* d_in, const int* in_sizes, int n_in,
                              void* d_out, int out_size, void* d_ws, size_t ws_size,
                              hipStream_t stream) {
  const float* z  = (const float*)d_in[0];  // (64,16)
  const float* W  = (const float*)d_in[1];  // (4,16)
  const float* wl = (const float*)d_in[2];  // (784,16)
  const float* bl = (const float*)d_in[3];  // (784,)
  float* out = (float*)d_out;               // (64,1,28,28) f32

  float* Pp = (float*)d_ws;                 // 256 blocks * 256 bins * 2 f32 = 512 KB

  kP <<<256, 256, 0, stream>>>(W, Pp);
  kBC<<<64, 256, 0, stream>>>(z, Pp, wl, bl, out);
}

// Round 6
// 81.043 us; speedup vs baseline: 1.5642x; 1.5642x over previous
//
#include <hip/hip_runtime.h>
#include <cstdint>

#define NQ 16
#define NL 4
#define NOUT 784
#define NX 65536
#define NCHUNK 64
#define IPER 4          // x-evals per kP thread = NX/(NCHUNK*256)

// ---------------------------------------------------------------------------
// Circuit algebra (verified on HW rounds 1 & 5, absmax 9.8e-4):
//   <Z_q>_s = 2^-16 Σ_bin [ cos(zp_s(bin))·C_q[bin] − sin(zp_s(bin))·S_q[bin] ]
//   (C,S)_q[bin] = Σ_{y over free bits} (cos,sin)( d_q(x(bin,y)) )   sample-indep
//   d_q(x) = Σ_{k: pc(v_k & m_q) odd} W_k (-1)^{pc(v_k & x)}
//   zp_s(bin) = Σ_{j in m_q} ±z_sj  (sign from bin bit j)
// Round-5 lesson: NO LDS atomics in the fold (39.7µs of contention);
// thread-owns-bin + register accumulation instead.
// ---------------------------------------------------------------------------
struct Tables {
  uint16_t m[NQ];
  int32_t  cnt[NQ];
  int32_t  pc[NQ];
  uint8_t  pos[NQ][16];     // positions of m bits
  uint8_t  posf[NQ][16];    // positions of free (non-m) bits
  uint16_t kmask[NQ][NL*NQ];
  uint8_t  kidx[NQ][NL*NQ];
  int32_t  off[NQ+1];       // flat (q,bin) offsets, off[NQ] = total bins
};

constexpr Tables make_tables() {
  Tables T{};
  uint16_t v[NL*NQ] = {};
  for (int l = 0; l < NL; l++)
    for (int q = 0; q < NQ; q++) {
      unsigned vv = 1u << q;
      for (int L = l - 1; L >= 0; --L)
        for (int k = NQ - 1; k >= 0; --k) {
          unsigned t = (unsigned)((k + 1) & (NQ - 1));
          if ((vv >> k) & 1u) vv ^= (1u << t);
        }
      v[l*NQ + q] = (uint16_t)vv;
    }
  for (int q = 0; q < NQ; q++) {
    unsigned mm = 1u << q;
    for (int L = NL - 1; L >= 0; --L)
      for (int k = NQ - 1; k >= 0; --k) {
        unsigned t = (unsigned)((k + 1) & (NQ - 1));
        if ((mm >> t) & 1u) mm ^= (1u << k);
      }
    T.m[q] = (uint16_t)mm;
  }
  for (int q = 0; q < NQ; q++) {
    int c = 0;
    for (int i = 0; i < NL*NQ; i++) {
      unsigned inter = (unsigned)(v[i] & T.m[q]);
      int pcnt = 0;
      for (int b = 0; b < 16; b++) pcnt += (int)((inter >> b) & 1u);
      if (pcnt & 1) { T.kmask[q][c] = v[i]; T.kidx[q][c] = (uint8_t)i; c++; }
    }
    T.cnt[q] = c;
  }
  for (int q = 0; q < NQ; q++) {
    int c = 0, f = 0;
    for (int b = 0; b < 16; b++) {
      if ((T.m[q] >> b) & 1u) T.pos[q][c++] = (uint8_t)b;
      else                    T.posf[q][f++] = (uint8_t)b;
    }
    T.pc[q] = c;
  }
  T.off[0] = 0;
  for (int q = 0; q < NQ; q++) T.off[q+1] = T.off[q] + (1 << T.pc[q]);
  return T;
}

constexpr Tables H_TAB = make_tables();
constexpr int max_pc() {
  int mx = 0;
  for (int q = 0; q < NQ; q++) if (H_TAB.pc[q] > mx) mx = H_TAB.pc[q];
  return mx;
}
constexpr int TOTALB = H_TAB.off[NQ];
static_assert(max_pc() <= 8, "G = 256>>pc would underflow");
static_assert(TOTALB <= 1024, "flat bin table exceeds one block");
static_assert(IPER * NCHUNK * 256 == NX, "x-space coverage");
__constant__ Tables TAB = H_TAB;

struct FlatT { uint8_t fq[1024]; };
constexpr FlatT make_flat() {
  FlatT F{};
  for (int q = 0; q < NQ; q++)
    for (int b = H_TAB.off[q]; b < H_TAB.off[q+1]; b++) F.fq[b] = (uint8_t)q;
  return F;
}
constexpr FlatT H_FLAT = make_flat();
__constant__ FlatT FLAT = H_FLAT;

// kP: 1024 blocks = 16 q * 64 chunks, 256 threads. Thread owns bin = t&(nb-1),
// group g = t>>pc; iterates IPER y-values; accumulates (C,S) in registers;
// writes its own Pp slot. No atomics, no LDS (except sW broadcast).
__global__ __launch_bounds__(256) void kP(const float* __restrict__ W,
                                          float* __restrict__ Pp) {
  __shared__ float sW[NL*NQ];
  int t = threadIdx.x;
  int b = blockIdx.x;
  int q = b >> 6;                   // NCHUNK = 64
  int chunk = b & (NCHUNK - 1);
  if (t < NL*NQ) sW[t] = W[t];
  __syncthreads();
  int n  = TAB.cnt[q];
  int pc = TAB.pc[q];
  int nb = 1 << pc;
  unsigned G = 256u >> pc;
  unsigned bin = (unsigned)t & (unsigned)(nb - 1);
  unsigned g   = (unsigned)t >> pc;
  unsigned xm = 0;
  for (int j = 0; j < pc; j++) xm |= ((bin >> j) & 1u) << TAB.pos[q][j];
  int nf = 16 - pc;
  float C = 0.f, S = 0.f;
  for (int i = 0; i < IPER; i++) {
    unsigned y = ((unsigned)(i * NCHUNK + chunk)) * G + g;
    unsigned x = xm;
    for (int j = 0; j < nf; j++) x |= ((y >> j) & 1u) << TAB.posf[q][j];
    float d0 = 0.f, d1 = 0.f;       // two chains to break dependence
    for (int k = 0; k + 1 < n; k += 2) {
      unsigned m0 = TAB.kmask[q][k];
      unsigned m1 = TAB.kmask[q][k+1];
      float w0 = sW[TAB.kidx[q][k]];
      float w1 = sW[TAB.kidx[q][k+1]];
      d0 += __uint_as_float(__float_as_uint(w0) ^ ((unsigned)(__popc(m0 & x) & 1) << 31));
      d1 += __uint_as_float(__float_as_uint(w1) ^ ((unsigned)(__popc(m1 & x) & 1) << 31));
    }
    if (n & 1) {
      unsigned m0 = TAB.kmask[q][n-1];
      float w0 = sW[TAB.kidx[q][n-1]];
      d0 += __uint_as_float(__float_as_uint(w0) ^ ((unsigned)(__popc(m0 & x) & 1) << 31));
    }
    float sn, cs;
    __sincosf(d0 + d1, &sn, &cs);
    C += cs; S += sn;
  }
  float2* P2 = (float2*)Pp;
  P2[((unsigned)b << 8) | (unsigned)t] = make_float2(C, S);
}

// kR: 16 blocks (one per q), 256 threads. Sum 64 chunk-partials per slot,
// then fold the G group copies per bin in LDS; write scaled PF[off[q]+bin].
__global__ __launch_bounds__(256) void kR(const float* __restrict__ Pp,
                                          float* __restrict__ PF) {
  __shared__ float sC[256], sS[256];
  int q = blockIdx.x, t = threadIdx.x;
  const float2* P2 = (const float2*)Pp;
  float C = 0.f, S = 0.f;
  #pragma unroll
  for (int c = 0; c < NCHUNK; c++) {
    float2 v = P2[(((unsigned)(q * NCHUNK + c)) << 8) | (unsigned)t];
    C += v.x; S += v.y;
  }
  sC[t] = C; sS[t] = S;
  __syncthreads();
  int pc = TAB.pc[q];
  int nb = 1 << pc;
  int G  = 256 >> pc;
  if (t < nb) {
    float c2 = 0.f, s2 = 0.f;
    for (int g = 0; g < G; g++) { c2 += sC[g*nb + t]; s2 += sS[g*nb + t]; }
    ((float2*)PF)[TAB.off[q] + t] =
        make_float2(c2 * (1.0f/65536.0f), s2 * (1.0f/65536.0f));
  }
}

// kBC: 64 blocks (one per sample), 1024 threads. Thread f < TOTALB handles one
// (q,bin): zp from sign pattern, sincos, term; 16-slot LDS atomic (864 adds,
// ~1µs). Then 784 outputs, one per thread: 16-FMA linear + tanh.
__global__ __launch_bounds__(1024) void kBC(const float* __restrict__ z,
                                            const float* __restrict__ PF,
                                            const float* __restrict__ wl,
                                            const float* __restrict__ bl,
                                            float* __restrict__ out) {
  __shared__ float sz[NQ];
  __shared__ float szq[NQ];
  int s = blockIdx.x, t = threadIdx.x;
  if (t < NQ) { sz[t] = z[s*NQ + t]; szq[t] = 0.f; }
  __syncthreads();
  if (t < TOTALB) {
    int q   = FLAT.fq[t];
    int bin = t - TAB.off[q];
    int pc  = TAB.pc[q];
    float zp = 0.f;
    for (int j = 0; j < pc; j++) {
      float v = sz[TAB.pos[q][j]];
      zp += ((bin >> j) & 1) ? -v : v;
    }
    float sn, cs;
    __sincosf(zp, &sn, &cs);
    float2 P = ((const float2*)PF)[t];
    atomicAdd(&szq[q], P.x * cs - P.y * sn);
  }
  __syncthreads();
  if (t < NOUT) {
    float acc = bl[t];
    const float* wr = wl + t*NQ;
    #pragma unroll
    for (int j = 0; j < NQ; j++) acc += szq[j] * wr[j];
    out[s*NOUT + t] = tanhf(acc);
  }
}

extern "C" void kernel_launch(void* const* d_in, const int* in_sizes, int n_in,
                              void* d_out, int out_size, void* d_ws, size_t ws_size,
                              hipStream_t stream) {
  const float* z  = (const float*)d_in[0];  // (64,16)
  const float* W  = (const float*)d_in[1];  // (4,16)
  const float* wl = (const float*)d_in[2];  // (784,16)
  const float* bl = (const float*)d_in[3];  // (784,)
  float* out = (float*)d_out;               // (64,1,28,28) f32

  float* Pp = (float*)d_ws;                 // 1024 blocks * 256 * float2 = 2 MB
  float* PF = Pp + (size_t)16 * NCHUNK * 256 * 2;  // 864 * float2

  kP <<<16 * NCHUNK, 256, 0, stream>>>(W, Pp);
  kR <<<NQ, 256, 0, stream>>>(Pp, PF);
  kBC<<<64, 1024, 0, stream>>>(z, PF, wl, bl, out);
}